// Round 16
// baseline (835.232 us; speedup 1.0000x reference)
//
#include <hip/hip_runtime.h>
#include <hip/hip_bf16.h>
#include <math.h>

#define N_PQ 65536
#define N_PV 16384
#define N_SL 64

typedef __attribute__((ext_vector_type(8))) short s16x8;
typedef __attribute__((ext_vector_type(4))) float f32x4;

__device__ __forceinline__ ushort f2bf(float f) {
    union { float f; unsigned u; } x; x.f = f;
    unsigned r = x.u + 0x7fff + ((x.u >> 16) & 1);
    return (ushort)(r >> 16);
}
__device__ __forceinline__ float bf2f(ushort u) {
    union { unsigned u; float f; } x; x.u = ((unsigned)u) << 16;
    return x.f;
}

// ---------------------------------------------------------------------------
// MFMA GEMM (round-10 body): C[M,N] = A[M,128] @ Bt[N,128] + bias
// ---------------------------------------------------------------------------
template<int OUT_BF16>
__global__ __launch_bounds__(256) void gemm_mfma(
    const ushort* __restrict__ A, const ushort* __restrict__ Bt,
    const float* __restrict__ bias, void* __restrict__ Cv, int M, int N)
{
    __shared__ ushort As[128 * 128];
    const int tid = threadIdx.x;
    const int m0 = blockIdx.x * 128;
    const int n0 = blockIdx.y * 128;

    #pragma unroll
    for (int p = 0; p < 8; ++p) {
        int c = p * 256 + tid;
        int row = c >> 4, c16 = c & 15;
        int gr = m0 + row;
        int4 v = make_int4(0, 0, 0, 0);
        if (gr < M) v = *(const int4*)(A + (size_t)gr * 128 + c16 * 8);
        *(int4*)(As + row * 128 + (c16 ^ (row & 7)) * 8) = v;
    }
    __syncthreads();

    const int lane = tid & 63, wave = tid >> 6;
    const int wr = wave >> 1, wc = wave & 1;
    const int lrow = lane & 15, lk = lane >> 4;

    f32x4 acc[4][4];
    #pragma unroll
    for (int mi = 0; mi < 4; ++mi)
        #pragma unroll
        for (int ni = 0; ni < 4; ++ni) acc[mi][ni] = (f32x4){0.f, 0.f, 0.f, 0.f};

    #pragma unroll
    for (int kk = 0; kk < 4; ++kk) {
        s16x8 a[4], b[4];
        #pragma unroll
        for (int mi = 0; mi < 4; ++mi) {
            int row = wr * 64 + mi * 16 + lrow;
            int c16 = (lk + kk * 4) ^ (row & 7);
            a[mi] = *(const s16x8*)(As + row * 128 + c16 * 8);
        }
        #pragma unroll
        for (int ni = 0; ni < 4; ++ni) {
            int n = n0 + wc * 64 + ni * 16 + lrow;
            b[ni] = *(const s16x8*)(Bt + (size_t)n * 128 + kk * 32 + lk * 8);
        }
        #pragma unroll
        for (int mi = 0; mi < 4; ++mi)
            #pragma unroll
            for (int ni = 0; ni < 4; ++ni)
                acc[mi][ni] = __builtin_amdgcn_mfma_f32_16x16x32_bf16(
                    a[mi], b[ni], acc[mi][ni], 0, 0, 0);
    }

    if (OUT_BF16) {
        __syncthreads();
        ushort* Cl = As;
        #pragma unroll
        for (int mi = 0; mi < 4; ++mi)
            #pragma unroll
            for (int ni = 0; ni < 4; ++ni)
                #pragma unroll
                for (int r = 0; r < 4; ++r) {
                    int row = wr * 64 + mi * 16 + (lane >> 4) * 4 + r;
                    int col = wc * 64 + ni * 16 + (lane & 15);
                    float v = acc[mi][ni][r] + (bias ? bias[n0 + col] : 0.f);
                    Cl[row * 128 + (((col >> 3) ^ (row & 7)) << 3) + (col & 7)] = f2bf(v);
                }
        __syncthreads();
        ushort* C = (ushort*)Cv;
        #pragma unroll
        for (int p = 0; p < 8; ++p) {
            int c = p * 256 + tid;
            int row = c >> 4, c16 = c & 15;
            int gr = m0 + row;
            if (gr < M)
                *(int4*)(C + (size_t)gr * N + n0 + c16 * 8) =
                    *(const int4*)(As + row * 128 + (c16 ^ (row & 7)) * 8);
        }
    } else {
        float* C = (float*)Cv;
        #pragma unroll
        for (int mi = 0; mi < 4; ++mi)
            #pragma unroll
            for (int ni = 0; ni < 4; ++ni)
                #pragma unroll
                for (int r = 0; r < 4; ++r) {
                    int row = m0 + wr * 64 + mi * 16 + (lane >> 4) * 4 + r;
                    int col = n0 + wc * 64 + ni * 16 + (lane & 15);
                    if (row < M)
                        C[(size_t)row * N + col] =
                            acc[mi][ni][r] + (bias ? bias[col] : 0.f);
                }
    }
}

// ---------------------------------------------------------------------------
// Panel GEMM: A staged once, NPAN col-panels per block, direct bf16 epilogue.
// ---------------------------------------------------------------------------
template<int NPAN>
__global__ __launch_bounds__(256) void gemm_pan(
    const ushort* __restrict__ A, const ushort* __restrict__ Bt,
    const float* __restrict__ bias, ushort* __restrict__ C, int M, int N)
{
    __shared__ ushort As[128 * 128];
    const int tid = threadIdx.x;
    const int m0 = blockIdx.x * 128;

    #pragma unroll
    for (int p = 0; p < 8; ++p) {
        int c = p * 256 + tid;
        int row = c >> 4, c16 = c & 15;
        *(int4*)(As + row * 128 + (c16 ^ (row & 7)) * 8) =
            *(const int4*)(A + (size_t)(m0 + row) * 128 + c16 * 8);
    }
    __syncthreads();

    const int lane = tid & 63, wave = tid >> 6;
    const int wr = wave >> 1, wc = wave & 1;
    const int lrow = lane & 15, lk = lane >> 4;

    #pragma unroll 1
    for (int pan = 0; pan < NPAN; ++pan) {
        const int n0 = (blockIdx.y * NPAN + pan) * 128;

        f32x4 acc[4][4];
        #pragma unroll
        for (int mi = 0; mi < 4; ++mi)
            #pragma unroll
            for (int ni = 0; ni < 4; ++ni) acc[mi][ni] = (f32x4){0.f, 0.f, 0.f, 0.f};

        #pragma unroll
        for (int kk = 0; kk < 4; ++kk) {
            s16x8 a[4], b[4];
            #pragma unroll
            for (int mi = 0; mi < 4; ++mi) {
                int row = wr * 64 + mi * 16 + lrow;
                int c16 = (lk + kk * 4) ^ (row & 7);
                a[mi] = *(const s16x8*)(As + row * 128 + c16 * 8);
            }
            #pragma unroll
            for (int ni = 0; ni < 4; ++ni) {
                int n = n0 + wc * 64 + ni * 16 + lrow;
                b[ni] = *(const s16x8*)(Bt + (size_t)n * 128 + kk * 32 + lk * 8);
            }
            #pragma unroll
            for (int mi = 0; mi < 4; ++mi)
                #pragma unroll
                for (int ni = 0; ni < 4; ++ni)
                    acc[mi][ni] = __builtin_amdgcn_mfma_f32_16x16x32_bf16(
                        a[mi], b[ni], acc[mi][ni], 0, 0, 0);
        }

        #pragma unroll
        for (int mi = 0; mi < 4; ++mi)
            #pragma unroll
            for (int ni = 0; ni < 4; ++ni) {
                int col = n0 + wc * 64 + ni * 16 + (lane & 15);
                float bv = bias ? bias[col] : 0.f;
                int row = m0 + wr * 64 + mi * 16 + (lane >> 4) * 4;
                ushort* cp = C + (size_t)row * N + col;
                #pragma unroll
                for (int r = 0; r < 4; ++r) {
                    *cp = f2bf(acc[mi][ni][r] + bv);
                    cp += N;
                }
            }
    }
}

// ---------------------------------------------------------------------------
// Weight prep (round-13 layout)
// ---------------------------------------------------------------------------
__global__ void prep_mats(
    const float* __restrict__ Wk, const float* __restrict__ Wq,
    const float* __restrict__ Wv, const float* __restrict__ Ws,
    const float* __restrict__ Wgt, const float* __restrict__ Wq1,
    const float* __restrict__ Wk2, const float* __restrict__ Wv2,
    const float* __restrict__ Wo,
    ushort* __restrict__ panels, ushort* __restrict__ wssum,
    ushort* __restrict__ finalw)
{
    const int m = blockIdx.x >> 6;
    const int e = (blockIdx.x & 63) * 256 + threadIdx.x;
    const int nl = e >> 7, k = e & 127;
    const int dstlist[3][3] = {{0,3,6},{1,4,7},{2,5,-1}};
    const int srclist[3][3] = {{0,1,2},{3,4,5},{6,7,-1}};
    const int nkg[3] = {3,3,2};
    const int gofs[3] = {0,1280,2560};

    if (m < 52) {
        int l = m / 26, r = m % 26;
        int g, slot;
        if (r < 10)      { g = 0; slot = r; }
        else if (r < 20) { g = 1; slot = r - 10; }
        else             { g = 2; slot = r - 20; }
        int nk = nkg[g];
        float val; int col;
        if (slot < nk) {
            int t = dstlist[g][slot];
            val = Wk[(size_t)(l * 8 + t) * 16384 + k * 128 + nl];
            col = slot * 128 + nl;
        } else if (slot < 2 * nk) {
            int s = slot - nk; int t = srclist[g][s];
            val = Wq[(size_t)(l * 8 + t) * 16384 + k * 128 + nl];
            col = nk * 128 + s * 256 + ((nl >> 1) << 2) + (nl & 1);
        } else if (slot < 3 * nk) {
            int s = slot - 2 * nk; int t = srclist[g][s];
            val = Wv[(size_t)(l * 8 + t) * 16384 + k * 128 + nl];
            col = nk * 128 + s * 256 + ((nl >> 1) << 2) + 2 + (nl & 1);
        } else {
            float s = 0.f;
            #pragma unroll
            for (int i = 0; i < 3; ++i) {
                int t = dstlist[g][i];
                if (t >= 0) s += Ws[(size_t)(l * 8 + t) * 16384 + k * 128 + nl];
            }
            val = s; col = 1152 + nl;
        }
        panels[((size_t)l * 3328 + gofs[g] + col) * 128 + k] = f2bf(val);
    } else if (m < 54) {
        int l = m - 52;
        float s = Ws[(size_t)(l * 8 + 2) * 16384 + k * 128 + nl]
                + Ws[(size_t)(l * 8 + 5) * 16384 + k * 128 + nl];
        wssum[(size_t)l * 16384 + nl * 128 + k] = f2bf(s);
    } else {
        const float* fsrc[5] = {Wgt, Wq1, Wk2, Wv2, Wo};
        int idx = m - 54;
        finalw[(size_t)idx * 16384 + nl * 128 + k] = f2bf(fsrc[idx][k * 128 + nl]);
    }
}

__global__ void prep_bias(
    const float* __restrict__ bk, const float* __restrict__ bq,
    const float* __restrict__ bv, const float* __restrict__ bconv,
    float* __restrict__ bias_cat, float* __restrict__ bcsum)
{
    const int l = blockIdx.x / 3, g = blockIdx.x % 3;
    const int dstlist[3][3] = {{0,3,6},{1,4,7},{2,5,-1}};
    const int srclist[3][3] = {{0,1,2},{3,4,5},{6,7,-1}};
    const int nkg[3] = {3,3,2};
    const int gofs[3] = {0,1280,2560};
    const int nslots = (g < 2) ? 10 : 6;
    int nk = nkg[g];
    for (int idx = threadIdx.x; idx < nslots * 128; idx += 256) {
        int slot = idx >> 7, nl = idx & 127;
        float val; int col;
        if (slot < nk) {
            int t = dstlist[g][slot];
            val = bk[(l * 8 + t) * 128 + nl];
            col = slot * 128 + nl;
        } else if (slot < 2 * nk) {
            int s = slot - nk; int t = srclist[g][s];
            val = bq[(l * 8 + t) * 128 + nl];
            col = nk * 128 + s * 256 + ((nl >> 1) << 2) + (nl & 1);
        } else if (slot < 3 * nk) {
            int s = slot - 2 * nk; int t = srclist[g][s];
            val = bv[(l * 8 + t) * 128 + nl];
            col = nk * 128 + s * 256 + ((nl >> 1) << 2) + 2 + (nl & 1);
        } else {
            float s = 0.f;
            #pragma unroll
            for (int i = 0; i < 3; ++i) {
                int t = dstlist[g][i];
                if (t >= 0) s += bconv[(l * 8 + t) * 128 + nl];
            }
            val = s; col = 1152 + nl;
        }
        bias_cat[l * 3328 + gofs[g] + col] = val;
    }
    if (g == 2 && threadIdx.x < 128) {
        bcsum[l * 128 + threadIdx.x] =
            bconv[(l * 8 + 2) * 128 + threadIdx.x] + bconv[(l * 8 + 5) * 128 + threadIdx.x];
    }
}

// ---------------------------------------------------------------------------
// CSR build: histogram -> parallel scan -> scatter (+bf16 ea scatter)
// ---------------------------------------------------------------------------
struct HArgs {
    const int* ei[6];
    const float* eav[6];
    int E[6];
    int base[6];
    int cum[7];
};

__global__ void hist_kernel(HArgs A, int* __restrict__ bins)
{
    int g = blockIdx.x * 256 + threadIdx.x;
    if (g >= A.cum[6]) return;
    int t = 0;
    #pragma unroll
    for (int i = 0; i < 5; ++i) t += (g >= A.cum[i + 1]);
    int e = g - A.cum[t];
    int dst = A.ei[t][A.E[t] + e];
    atomicAdd(&bins[A.base[t] + dst], 1);
}

__global__ __launch_bounds__(256) void scan_a(
    const int* __restrict__ bins, int* __restrict__ offs, int* __restrict__ bsum)
{
    __shared__ int s[256];
    const int b = blockIdx.x, t = threadIdx.x;
    int v = bins[b * 256 + t];
    s[t] = v; __syncthreads();
    #pragma unroll
    for (int off = 1; off < 256; off <<= 1) {
        int x = (t >= off) ? s[t - off] : 0;
        __syncthreads();
        s[t] += x;
        __syncthreads();
    }
    offs[b * 256 + t] = s[t] - v;
    if (t == 255) bsum[b] = s[255];
}

__global__ __launch_bounds__(1024) void scan_b(
    const int* __restrict__ bsum, int* __restrict__ carry)
{
    __shared__ int s[1024];
    const int t = threadIdx.x;
    int v = bsum[t];
    s[t] = v; __syncthreads();
    for (int off = 1; off < 1024; off <<= 1) {
        int x = (t >= off) ? s[t - off] : 0;
        __syncthreads();
        s[t] += x;
        __syncthreads();
    }
    carry[t] = s[t] - v;
}

__global__ void scan_c(int* __restrict__ offs, const int* __restrict__ carry,
                       int* __restrict__ cursor)
{
    const int b = blockIdx.x, t = threadIdx.x;
    int v = offs[b * 256 + t] + carry[b];
    offs[b * 256 + t] = v;
    cursor[b * 256 + t] = v;
}

__global__ void scatter_kernel(HArgs A, int* __restrict__ cursor,
                               int* __restrict__ lsrc, int* __restrict__ leid,
                               ushort* __restrict__ eascat)
{
    int g = blockIdx.x * 256 + threadIdx.x;
    if (g >= A.cum[6]) return;
    int t = 0;
    #pragma unroll
    for (int i = 0; i < 5; ++i) t += (g >= A.cum[i + 1]);
    int e = g - A.cum[t];
    int src = A.ei[t][e];
    int dst = A.ei[t][A.E[t] + e];
    int pos = atomicAdd(&cursor[A.base[t] + dst], 1);
    lsrc[pos] = src;
    leid[pos] = e;
    if (eascat) {
        const float* eap = A.eav[t] + (size_t)e * 16;
        s16x8 lo, hi;
        #pragma unroll
        for (int r = 0; r < 8; ++r) {
            lo[r] = (short)f2bf(eap[r]);
            hi[r] = (short)f2bf(eap[r + 8]);
        }
        *(s16x8*)(eascat + (size_t)pos * 16) = lo;
        *(s16x8*)(eascat + (size_t)pos * 16 + 8) = hi;
    }
}

// ---------------------------------------------------------------------------
// CSR gather bodies
// ---------------------------------------------------------------------------
struct GTA {
    int base, kcol, qvcol, lds;
    const ushort* Ys;
    const float* ea;
    const float* We;
    const float* be;
};
struct GArgs {
    GTA t[3];
    const int* offs;
    const int* lsrc;
    const int* leid;
    const ushort* eascat;
    ushort* xbg;
    const ushort* Yg;
    int ldg, wscol;
};

// depth-4 pipeline over each type's CSR segment (SEQEA path)
__device__ __forceinline__ void gather_body_seq(const GArgs& A, int d, int lane)
{
    const int j0 = lane * 2;
    ushort2 w2 = *(const ushort2*)(A.Yg + (size_t)d * A.ldg + A.wscol + j0);
    float a0 = bf2f(w2.x), a1 = bf2f(w2.y);

    #pragma unroll
    for (int i = 0; i < 3; ++i) {
        const GTA T = A.t[i];
        int start = __builtin_amdgcn_readfirstlane(A.offs[T.base + d]);
        int end   = __builtin_amdgcn_readfirstlane(A.offs[T.base + d + 1]);
        if (start == end) continue;

        ushort2 kk = *(const ushort2*)(A.Yg + (size_t)d * A.ldg + T.kcol + j0);
        float k0 = bf2f(kk.x), k1 = bf2f(kk.y);
        float we0[16], we1[16];
        #pragma unroll
        for (int r = 0; r < 16; ++r) {
            float2 wv = *(const float2*)(T.We + r * 128 + j0);
            we0[r] = wv.x; we1[r] = wv.y;
        }
        float2 be2 = *(const float2*)(T.be + j0);

        #define LOAD_SLOT(IDX, QV, LO, HI) { \
            int _si = __builtin_amdgcn_readfirstlane(A.lsrc[IDX]); \
            QV = *(const uint2*)(T.Ys + (size_t)_si * T.lds + T.qvcol + lane * 4); \
            LO = *(const s16x8*)(A.eascat + (size_t)(IDX) * 16); \
            HI = *(const s16x8*)(A.eascat + (size_t)(IDX) * 16 + 8); }

        #define COMPUTE_SEQ(QV, LO, HI) { \
            float c[16]; \
            _Pragma("unroll") \
            for (int r = 0; r < 8; ++r) { \
                c[r]     = bf2f((ushort)(LO)[r]); \
                c[r + 8] = bf2f((ushort)(HI)[r]); \
            } \
            float e0 = be2.x, e1 = be2.y; \
            _Pragma("unroll") \
            for (int r = 0; r < 16; ++r) { \
                e0 = fmaf(c[r], we0[r], e0); \
                e1 = fmaf(c[r], we1[r], e1); \
            } \
            float q0 = bf2f((ushort)((QV).x & 0xffff)), q1 = bf2f((ushort)((QV).x >> 16)); \
            float v0 = bf2f((ushort)((QV).y & 0xffff)), v1 = bf2f((ushort)((QV).y >> 16)); \
            float g0 = 1.f / (1.f + __expf(-(k0 + q0 + e0))); \
            float g1 = 1.f / (1.f + __expf(-(k1 + q1 + e1))); \
            a0 = fmaf(g0, v0, a0); \
            a1 = fmaf(g1, v1, a1); }

        uint2 qvA, qvB, qvC, qvD;
        s16x8 loA, hiA, loB, hiB, loC, hiC, loD, hiD;
        int last = end - 1;
        int iB = (start + 1 < end) ? start + 1 : last;
        int iC = (start + 2 < end) ? start + 2 : last;
        int iD = (start + 3 < end) ? start + 3 : last;
        LOAD_SLOT(start, qvA, loA, hiA)
        LOAD_SLOT(iB,    qvB, loB, hiB)
        LOAD_SLOT(iC,    qvC, loC, hiC)
        LOAD_SLOT(iD,    qvD, loD, hiD)

        for (int e = start; e < end; e += 4) {
            // consume A..D for edges e..e+3; prefetch e+4..e+7
            uint2 qa = qvA; s16x8 la = loA, ha = hiA;
            int nA = (e + 4 < end) ? e + 4 : last;
            LOAD_SLOT(nA, qvA, loA, hiA)
            COMPUTE_SEQ(qa, la, ha)

            if (e + 1 < end) {
                uint2 qb = qvB; s16x8 lb = loB, hb = hiB;
                int nB = (e + 5 < end) ? e + 5 : last;
                LOAD_SLOT(nB, qvB, loB, hiB)
                COMPUTE_SEQ(qb, lb, hb)
            }
            if (e + 2 < end) {
                uint2 qc = qvC; s16x8 lc = loC, hc = hiC;
                int nC = (e + 6 < end) ? e + 6 : last;
                LOAD_SLOT(nC, qvC, loC, hiC)
                COMPUTE_SEQ(qc, lc, hc)
            }
            if (e + 3 < end) {
                uint2 qd = qvD; s16x8 ld = loD, hd = hiD;
                int nD = (e + 7 < end) ? e + 7 : last;
                LOAD_SLOT(nD, qvD, loD, hiD)
                COMPUTE_SEQ(qd, ld, hd)
            }
        }
        #undef COMPUTE_SEQ
        #undef LOAD_SLOT
    }
    ushort2 o; o.x = f2bf(fmaxf(a0, 0.f)); o.y = f2bf(fmaxf(a1, 0.f));
    *(ushort2*)(A.xbg + (size_t)d * 128 + j0) = o;
}

// merged two-group gather (SEQEA path)
struct G2Args {
    GArgs g0;
    GArgs g1;
    int nblk0;
};

__global__ __launch_bounds__(256) void gather2_kernel(G2Args P)
{
    const int wave = threadIdx.x >> 6, lane = threadIdx.x & 63;
    if ((int)blockIdx.x < P.nblk0) {
        gather_body_seq(P.g0, blockIdx.x * 4 + wave, lane);
    } else {
        gather_body_seq(P.g1, (blockIdx.x - P.nblk0) * 4 + wave, lane);
    }
}

// fallback: leid-based gather (only used if eascat doesn't fit in ws)
__global__ __launch_bounds__(256) void gather_kernel0(GArgs A)
{
    const int wave = threadIdx.x >> 6, lane = threadIdx.x & 63;
    const int d = blockIdx.x * 4 + wave;
    const int j0 = lane * 2;

    ushort2 w2 = *(const ushort2*)(A.Yg + (size_t)d * A.ldg + A.wscol + j0);
    float a0 = bf2f(w2.x), a1 = bf2f(w2.y);

    #pragma unroll
    for (int i = 0; i < 3; ++i) {
        const GTA T = A.t[i];
        int start = __builtin_amdgcn_readfirstlane(A.offs[T.base + d]);
        int end   = __builtin_amdgcn_readfirstlane(A.offs[T.base + d + 1]);
        if (start == end) continue;

        ushort2 kk = *(const ushort2*)(A.Yg + (size_t)d * A.ldg + T.kcol + j0);
        float k0 = bf2f(kk.x), k1 = bf2f(kk.y);
        float we0[16], we1[16];
        #pragma unroll
        for (int r = 0; r < 16; ++r) {
            float2 wv = *(const float2*)(T.We + r * 128 + j0);
            we0[r] = wv.x; we1[r] = wv.y;
        }
        float2 be2 = *(const float2*)(T.be + j0);

        for (int e = start; e < end; ++e) {
            int si  = __builtin_amdgcn_readfirstlane(A.lsrc[e]);
            int eid = __builtin_amdgcn_readfirstlane(A.leid[e]);
            uint2 qv = *(const uint2*)(T.Ys + (size_t)si * T.lds + T.qvcol + lane * 4);
            float4 c0 = *(const float4*)(T.ea + (size_t)eid * 16);
            float4 c1 = *(const float4*)(T.ea + (size_t)eid * 16 + 4);
            float4 c2 = *(const float4*)(T.ea + (size_t)eid * 16 + 8);
            float4 c3 = *(const float4*)(T.ea + (size_t)eid * 16 + 12);
            float e0 = be2.x, e1 = be2.y;
            e0 += c0.x*we0[0] + c0.y*we0[1] + c0.z*we0[2] + c0.w*we0[3]
                + c1.x*we0[4] + c1.y*we0[5] + c1.z*we0[6] + c1.w*we0[7]
                + c2.x*we0[8] + c2.y*we0[9] + c2.z*we0[10] + c2.w*we0[11]
                + c3.x*we0[12] + c3.y*we0[13] + c3.z*we0[14] + c3.w*we0[15];
            e1 += c0.x*we1[0] + c0.y*we1[1] + c0.z*we1[2] + c0.w*we1[3]
                + c1.x*we1[4] + c1.y*we1[5] + c1.z*we1[6] + c1.w*we1[7]
                + c2.x*we1[8] + c2.y*we1[9] + c2.z*we1[10] + c2.w*we1[11]
                + c3.x*we1[12] + c3.y*we1[13] + c3.z*we1[14] + c3.w*we1[15];
            float q0 = bf2f((ushort)(qv.x & 0xffff)), q1 = bf2f((ushort)(qv.x >> 16));
            float v0 = bf2f((ushort)(qv.y & 0xffff)), v1 = bf2f((ushort)(qv.y >> 16));
            float g0 = 1.f / (1.f + __expf(-(k0 + q0 + e0)));
            float g1 = 1.f / (1.f + __expf(-(k1 + q1 + e1)));
            a0 = fmaf(g0, v0, a0);
            a1 = fmaf(g1, v1, a1);
        }
    }
    ushort2 o; o.x = f2bf(fmaxf(a0, 0.f)); o.y = f2bf(fmaxf(a1, 0.f));
    *(ushort2*)(A.xbg + (size_t)d * 128 + j0) = o;
}

// ---------------------------------------------------------------------------
// Atomic edge kernel for Slack-destination types (qv quad-interleaved layout)
// ---------------------------------------------------------------------------
__global__ __launch_bounds__(256) void edge_slack(
    const int* __restrict__ ei, const float* __restrict__ ea,
    const float* __restrict__ We, const float* __restrict__ be,
    const ushort* __restrict__ Yk, int ldk,
    const ushort* __restrict__ Yqv, int ldq,
    float* __restrict__ nd, int E)
{
    const int e = blockIdx.x * 2 + (threadIdx.x >> 7);
    if (e >= E) return;
    const int j = threadIdx.x & 127;
    const int si = ei[e];
    const int di = ei[E + e];

    float ej = be[j];
    #pragma unroll
    for (int r = 0; r < 16; ++r)
        ej += ea[(size_t)e * 16 + r] * We[r * 128 + j];

    float kv = bf2f(Yk[(size_t)di * ldk + j]);
    float qv = bf2f(Yqv[(size_t)si * ldq + ((j >> 1) << 2) + (j & 1)]);
    float vv = bf2f(Yqv[(size_t)si * ldq + ((j >> 1) << 2) + 2 + (j & 1)]);
    float g  = 1.f / (1.f + __expf(-(kv + qv + ej)));
    atomicAdd(&nd[(size_t)di * 128 + j], g * vv);
}

// ---------------------------------------------------------------------------
// Elementwise helpers
// ---------------------------------------------------------------------------
__global__ void f2b_kernel(const float* __restrict__ a, ushort* __restrict__ o, int n)
{
    int i = (blockIdx.x * 256 + threadIdx.x) * 4;
    if (i < n) {
        float4 v = *(const float4*)(a + i);
        ushort4 u; u.x = f2bf(v.x); u.y = f2bf(v.y); u.z = f2bf(v.z); u.w = f2bf(v.w);
        *(ushort4*)(o + i) = u;
    }
}
__global__ void relu_b_kernel(const float* __restrict__ a, ushort* __restrict__ o, int n)
{
    int i = (blockIdx.x * 256 + threadIdx.x) * 4;
    if (i < n) {
        float4 v = *(const float4*)(a + i);
        ushort4 u;
        u.x = f2bf(fmaxf(v.x, 0.f)); u.y = f2bf(fmaxf(v.y, 0.f));
        u.z = f2bf(fmaxf(v.z, 0.f)); u.w = f2bf(fmaxf(v.w, 0.f));
        *(ushort4*)(o + i) = u;
    }
}
__global__ void b2f_kernel(const ushort* __restrict__ a, float* __restrict__ o, int n)
{
    int i = blockIdx.x * 256 + threadIdx.x;
    if (i < n) o[i] = bf2f(a[i]);
}

// ---------------------------------------------------------------------------
// Global pooling (bf16): two-stage mean+max
// ---------------------------------------------------------------------------
__global__ void pool1(const ushort* __restrict__ gf, float* __restrict__ pbuf)
{
    const int b = blockIdx.x >> 4, c = blockIdx.x & 15;
    const int j = threadIdx.x;
    float s = 0.f, m = -INFINITY;
    const ushort* pq = gf + (size_t)(b * 1024 + c * 64) * 128;
    for (int i = 0; i < 64; ++i) { float v = bf2f(pq[i * 128 + j]); s += v; m = fmaxf(m, v); }
    const ushort* pv = gf + (size_t)(N_PQ + b * 256 + c * 16) * 128;
    for (int i = 0; i < 16; ++i) { float v = bf2f(pv[i * 128 + j]); s += v; m = fmaxf(m, v); }
    if (c == 0) { float v = bf2f(gf[(size_t)(N_PQ + N_PV + b) * 128 + j]); s += v; m = fmaxf(m, v); }
    pbuf[(size_t)blockIdx.x * 256 + j] = s;
    pbuf[(size_t)blockIdx.x * 256 + 128 + j] = m;
}
__global__ void pool2(const float* __restrict__ pbuf, float* __restrict__ gnode)
{
    const int b = blockIdx.x, j = threadIdx.x;
    float s = 0.f, m = -INFINITY;
    for (int c = 0; c < 16; ++c) {
        s += pbuf[(size_t)(b * 16 + c) * 256 + j];
        m = fmaxf(m, pbuf[(size_t)(b * 16 + c) * 256 + 128 + j]);
    }
    gnode[(size_t)(b * 2) * 128 + j]     = s * (1.f / 1281.f);
    gnode[(size_t)(b * 2 + 1) * 128 + j] = m;
}

// ---------------------------------------------------------------------------
// Cross-attention (2 keys)
// ---------------------------------------------------------------------------
__global__ __launch_bounds__(256) void attn_kernel(
    const ushort* __restrict__ q, const float* __restrict__ k2,
    const float* __restrict__ v2, ushort* __restrict__ ao, int shift, int Ntot)
{
    const int n = blockIdx.x * 2 + (threadIdx.x >> 7);
    if (n >= Ntot) return;
    const int j = threadIdx.x & 127;
    const int b = n >> shift;
    const int h16 = j & ~15;

    const ushort* qn = q + (size_t)n * 128 + h16;
    const float* k0 = k2 + (size_t)(b * 2) * 128 + h16;
    const float* k1 = k2 + (size_t)(b * 2 + 1) * 128 + h16;
    float s0 = 0.f, s1 = 0.f;
    #pragma unroll
    for (int d = 0; d < 16; ++d) {
        float qq = bf2f(qn[d]); s0 += qq * k0[d]; s1 += qq * k1[d];
    }
    s0 *= 0.25f; s1 *= 0.25f;
    float m  = fmaxf(s0, s1);
    float a0 = __expf(s0 - m), a1 = __expf(s1 - m);
    float inv = 1.f / (a0 + a1);
    ao[(size_t)n * 128 + j] = f2bf(
        (a0 * v2[(size_t)(b * 2) * 128 + j] + a1 * v2[(size_t)(b * 2 + 1) * 128 + j]) * inv);
}

// ---------------------------------------------------------------------------
// LayerNorm (ca in bf16)
// ---------------------------------------------------------------------------
__global__ __launch_bounds__(256) void ln_kernel(
    const ushort* __restrict__ x, const ushort* __restrict__ ca,
    const float* __restrict__ g, const float* __restrict__ bb,
    float* __restrict__ out, int N)
{
    const int n = blockIdx.x * 4 + (threadIdx.x >> 6);
    if (n >= N) return;
    const int l = threadIdx.x & 63;
    const size_t base = (size_t)n * 128;
    float h0 = bf2f(x[base + l * 2])     + bf2f(ca[base + l * 2]);
    float h1 = bf2f(x[base + l * 2 + 1]) + bf2f(ca[base + l * 2 + 1]);
    float s  = h0 + h1;
    float ss = h0 * h0 + h1 * h1;
    #pragma unroll
    for (int o = 32; o; o >>= 1) { s += __shfl_xor(s, o); ss += __shfl_xor(ss, o); }
    float mu  = s * (1.f / 128.f);
    float var = ss * (1.f / 128.f) - mu * mu;
    float rs  = rsqrtf(var + 1e-5f);
    out[base + l * 2]     = (h0 - mu) * rs * g[l * 2]     + bb[l * 2];
    out[base + l * 2 + 1] = (h1 - mu) * rs * g[l * 2 + 1] + bb[l * 2 + 1];
}

// ---------------------------------------------------------------------------
// Host orchestration
// ---------------------------------------------------------------------------
extern "C" void kernel_launch(void* const* d_in, const int* in_sizes, int n_in,
                              void* d_out, int out_size, void* d_ws, size_t ws_size,
                              hipStream_t stream)
{
    const float* xin[3] = {(const float*)d_in[0], (const float*)d_in[1], (const float*)d_in[2]};
    const int NNs[3] = {N_PQ, N_PV, N_SL};
    const int ncol[3] = {1280, 1280, 768};
    const int gofs[3] = {0, 1280, 2560};

    const int*   ei[8];
    const float* ea[8];
    int          Ecnt[8];
    for (int t = 0; t < 8; ++t) {
        ei[t]   = (const int*)d_in[3 + 2 * t];
        ea[t]   = (const float*)d_in[4 + 2 * t];
        Ecnt[t] = in_sizes[3 + 2 * t] / 2;
    }
    const float* Wk    = (const float*)d_in[19];
    const float* bk    = (const float*)d_in[20];
    const float* Wq    = (const float*)d_in[21];
    const float* bq    = (const float*)d_in[22];
    const float* Wv    = (const float*)d_in[23];
    const float* bv    = (const float*)d_in[24];
    const float* Ws    = (const float*)d_in[25];
    const float* bconv = (const float*)d_in[26];
    const float* We    = (const float*)d_in[27];
    const float* be    = (const float*)d_in[28];
    const float* Wgt   = (const float*)d_in[29];
    const float* bgt   = (const float*)d_in[30];
    const float* Wq1   = (const float*)d_in[31];
    const float* Wk2   = (const float*)d_in[32];
    const float* Wv2   = (const float*)d_in[33];
    const float* Wo    = (const float*)d_in[34];
    const float* bo    = (const float*)d_in[35];
    const float* ln_g  = (const float*)d_in[36];
    const float* ln_b  = (const float*)d_in[37];

    // ---- workspace carve-up (round-13 layout) ----
    char* w = (char*)d_ws;
    ushort* Y[3];
    Y[0] = (ushort*)w; w += (size_t)N_PQ * 1280 * 2;
    Y[1] = (ushort*)w; w += (size_t)N_PV * 1280 * 2;
    Y[2] = (ushort*)w; w += (size_t)N_SL * 768 * 2;
    ushort* xb[3];
    xb[0] = (ushort*)w; w += (size_t)N_PQ * 128 * 2;
    xb[1] = (ushort*)w; w += (size_t)N_PV * 128 * 2;
    xb[2] = (ushort*)w; w += (size_t)N_SL * 128 * 2;
    ushort* panels = (ushort*)w; w += (size_t)2 * 3328 * 128 * 2;
    ushort* wssum  = (ushort*)w; w += (size_t)2 * 16384 * 2;
    ushort* finalw = (ushort*)w; w += (size_t)5 * 16384 * 2;
    float* bias_cat = (float*)w; w += 6656 * 4;
    float* bcsum    = (float*)w; w += 256 * 4;
    float* gnode    = (float*)w; w += 16384 * 4;
    ushort* gnodeb  = (ushort*)w; w += 16384 * 2;
    float* k2       = (float*)w; w += 16384 * 4;
    float* v2       = (float*)w; w += 16384 * 4;
    float* pbuf     = (float*)w; w += 1024 * 256 * 4;
    const int NBINS = 262144;
    int* bins   = (int*)w; w += (size_t)NBINS * 4;
    int* offs   = (int*)w; w += (size_t)NBINS * 4;
    int* cursor = (int*)w; w += (size_t)NBINS * 4;
    int* bsum   = (int*)w; w += 1024 * 4;
    int* carry  = (int*)w; w += 1024 * 4;
    int* lsrc   = (int*)w; w += (size_t)600064 * 4;
    int* leid   = (int*)w; w += (size_t)600064 * 4;
    size_t base_bytes = (size_t)(w - (char*)d_ws);
    size_t eascat_bytes = (size_t)600064 * 16 * 2;
    ushort* eascat = nullptr;
    if (base_bytes + eascat_bytes <= ws_size) {
        eascat = (ushort*)w; w += eascat_bytes;
    }
    // overlays into Y[0]:
    ushort* gf    = Y[0];
    ushort* qb    = Y[0];
    ushort* ao    = Y[0] + (size_t)81920 * 128;
    ushort* cbufb = Y[0] + (size_t)2 * 81920 * 128;
    float* outp = (float*)d_out;
    float* nw2 = outp + (size_t)(N_PQ + N_PV) * 128;

    const ushort* Wgt_t = finalw;
    const ushort* Wq1_t = finalw + 16384;
    const ushort* Wk2_t = finalw + 32768;
    const ushort* Wv2_t = finalw + 49152;
    const ushort* Wo_t  = finalw + 65536;

    auto gemm_b = [&](const ushort* A, const ushort* Bt, const float* bias,
                      ushort* C, int M, int N) {
        if (M >= 1024 && N % 256 == 0)
            gemm_pan<2><<<dim3(M / 128, N / 256), 256, 0, stream>>>(A, Bt, bias, C, M, N);
        else if (M >= 1024 && M % 128 == 0 && N % 128 == 0)
            gemm_pan<1><<<dim3(M / 128, N / 128), 256, 0, stream>>>(A, Bt, bias, C, M, N);
        else
            gemm_mfma<1><<<dim3((M + 127) / 128, N / 128), 256, 0, stream>>>(
                A, Bt, bias, C, M, N);
    };
    auto gemm_f = [&](const ushort* A, const ushort* Bt, const float* bias,
                      float* C, int M, int N) {
        gemm_mfma<0><<<dim3((M + 127) / 128, N / 128), 256, 0, stream>>>(A, Bt, bias, C, M, N);
    };

    // 1) weight prep + input converts
    prep_mats<<<59 * 64, 256, 0, stream>>>(Wk, Wq, Wv, Ws, Wgt, Wq1, Wk2, Wv2, Wo,
                                           panels, wssum, finalw);
    prep_bias<<<6, 256, 0, stream>>>(bk, bq, bv, bconv, bias_cat, bcsum);
    for (int g = 0; g < 3; ++g) {
        int n = NNs[g] * 128;
        f2b_kernel<<<dim3((n / 4 + 255) / 256), 256, 0, stream>>>(xin[g], xb[g], n);
    }

    // 2) CSR build
    const int csr_t[6]    = {0, 3, 6, 1, 4, 7};
    const int csr_base[6] = {0, 65536, 131072, 196608, 212992, 229376};
    HArgs ha;
    {
        int c = 0;
        for (int i = 0; i < 6; ++i) {
            int t = csr_t[i];
            ha.ei[i] = ei[t]; ha.eav[i] = ea[t];
            ha.E[i] = Ecnt[t]; ha.base[i] = csr_base[i];
            ha.cum[i] = c; c += Ecnt[t];
        }
        ha.cum[6] = c;
    }
    hipMemsetAsync(bins, 0, (size_t)NBINS * 4, stream);
    hist_kernel<<<dim3((ha.cum[6] + 255) / 256), 256, 0, stream>>>(ha, bins);
    scan_a<<<1024, 256, 0, stream>>>(bins, offs, bsum);
    scan_b<<<1, 1024, 0, stream>>>(bsum, carry);
    scan_c<<<1024, 256, 0, stream>>>(offs, carry, cursor);
    scatter_kernel<<<dim3((ha.cum[6] + 255) / 256), 256, 0, stream>>>(
        ha, cursor, lsrc, leid, eascat);

    // 3) global features
    gemm_b(xb[0], Wgt_t, bgt, gf, N_PQ + N_PV + N_SL, 128);
    pool1<<<1024, 128, 0, stream>>>(gf, pbuf);
    pool2<<<64, 128, 0, stream>>>(pbuf, gnode);
    f2b_kernel<<<dim3(16384 / 4 / 256), 256, 0, stream>>>(gnode, gnodeb, 16384);
    gemm_f(gnodeb, Wk2_t, nullptr, k2, 128, 128);
    gemm_f(gnodeb, Wv2_t, nullptr, v2, 128, 128);

    // 4) two HeteroConv layers
    for (int l = 0; l < 2; ++l) {
        for (int g = 0; g < 3; ++g)
            gemm_b(xb[g], panels + ((size_t)l * 3328 + gofs[g]) * 128,
                   bias_cat + l * 3328 + gofs[g], Y[g], NNs[g], ncol[g]);
        gemm_f(xb[2], wssum + (size_t)l * 16384, bcsum + l * 128, nw2, N_SL, 128);

        // CSR gathers: merged PQ+PV launch (or per-group fallback)
        GArgs ga[2];
        for (int g = 0; g < 2; ++g) {
            for (int i = 0; i < 3; ++i) {
                int t = csr_t[g * 3 + i], off = l * 8 + t;
                int sgrp = (i == 2) ? 2 : i;
                ga[g].t[i].base  = csr_base[g * 3 + i];
                ga[g].t[i].kcol  = i * 128;
                ga[g].t[i].lds   = ncol[sgrp];
                ga[g].t[i].qvcol = ((sgrp == 2) ? 256 : 384) + g * 256;
                ga[g].t[i].Ys    = Y[sgrp];
                ga[g].t[i].ea    = ea[t];
                ga[g].t[i].We    = We + (size_t)off * 2048;
                ga[g].t[i].be    = be + (size_t)off * 128;
            }
            ga[g].offs = offs; ga[g].lsrc = lsrc; ga[g].leid = leid;
            ga[g].eascat = eascat;
            ga[g].xbg = xb[g]; ga[g].Yg = Y[g]; ga[g].ldg = ncol[g];
            ga[g].wscol = 1152;
        }
        if (eascat) {
            G2Args p2; p2.g0 = ga[0]; p2.g1 = ga[1]; p2.nblk0 = N_PQ / 4;
            gather2_kernel<<<dim3((N_PQ + N_PV) / 4), 256, 0, stream>>>(p2);
        } else {
            gather_kernel0<<<dim3(N_PQ / 4), 256, 0, stream>>>(ga[0]);
            gather_kernel0<<<dim3(N_PV / 4), 256, 0, stream>>>(ga[1]);
        }

        // Slack destination: tiny atomic path (types 2 and 5) + relu
        {
            int off2 = l * 8 + 2;
            edge_slack<<<dim3((Ecnt[2] + 1) / 2), 256, 0, stream>>>(
                ei[2], ea[2], We + (size_t)off2 * 2048, be + (size_t)off2 * 128,
                Y[2] + 0, 768, Y[0] + 896, 1280, nw2, Ecnt[2]);
            int off5 = l * 8 + 5;
            edge_slack<<<dim3((Ecnt[5] + 1) / 2), 256, 0, stream>>>(
                ei[5], ea[5], We + (size_t)off5 * 2048, be + (size_t)off5 * 128,
                Y[2] + 128, 768, Y[1] + 896, 1280, nw2, Ecnt[5]);
        }
        relu_b_kernel<<<dim3(8), 256, 0, stream>>>(nw2, xb[2], N_SL * 128);
    }

    // 5) cross-attention + residual + LayerNorm (merged over PQ+PV)
    gemm_b(xb[0], Wq1_t, nullptr, qb, N_PQ + N_PV, 128);
    attn_kernel<<<dim3(N_PQ / 2), 256, 0, stream>>>(qb, k2, v2, ao, 10, N_PQ);
    attn_kernel<<<dim3(N_PV / 2), 256, 0, stream>>>(qb + (size_t)N_PQ * 128, k2, v2,
                                                    ao + (size_t)N_PQ * 128, 8, N_PV);
    gemm_b(ao, Wo_t, bo, cbufb, N_PQ + N_PV, 128);
    ln_kernel<<<dim3((N_PQ + N_PV) / 4), 256, 0, stream>>>(xb[0], cbufb, ln_g, ln_b,
                                                           outp, N_PQ + N_PV);
    b2f_kernel<<<dim3((N_SL * 128 + 255) / 256), 256, 0, stream>>>(
        xb[2], outp + (size_t)(N_PQ + N_PV) * 128, N_SL * 128);
}

// Round 17
// 822.314 us; speedup vs baseline: 1.0157x; 1.0157x over previous
//
#include <hip/hip_runtime.h>
#include <hip/hip_bf16.h>
#include <math.h>

#define N_PQ 65536
#define N_PV 16384
#define N_SL 64

typedef __attribute__((ext_vector_type(8))) short s16x8;
typedef __attribute__((ext_vector_type(4))) float f32x4;

__device__ __forceinline__ ushort f2bf(float f) {
    union { float f; unsigned u; } x; x.f = f;
    unsigned r = x.u + 0x7fff + ((x.u >> 16) & 1);
    return (ushort)(r >> 16);
}
__device__ __forceinline__ float bf2f(ushort u) {
    union { unsigned u; float f; } x; x.u = ((unsigned)u) << 16;
    return x.f;
}

// ---------------------------------------------------------------------------
// MFMA GEMM (round-10 body): C[M,N] = A[M,128] @ Bt[N,128] + bias
// ---------------------------------------------------------------------------
template<int OUT_BF16>
__global__ __launch_bounds__(256) void gemm_mfma(
    const ushort* __restrict__ A, const ushort* __restrict__ Bt,
    const float* __restrict__ bias, void* __restrict__ Cv, int M, int N)
{
    __shared__ ushort As[128 * 128];
    const int tid = threadIdx.x;
    const int m0 = blockIdx.x * 128;
    const int n0 = blockIdx.y * 128;

    #pragma unroll
    for (int p = 0; p < 8; ++p) {
        int c = p * 256 + tid;
        int row = c >> 4, c16 = c & 15;
        int gr = m0 + row;
        int4 v = make_int4(0, 0, 0, 0);
        if (gr < M) v = *(const int4*)(A + (size_t)gr * 128 + c16 * 8);
        *(int4*)(As + row * 128 + (c16 ^ (row & 7)) * 8) = v;
    }
    __syncthreads();

    const int lane = tid & 63, wave = tid >> 6;
    const int wr = wave >> 1, wc = wave & 1;
    const int lrow = lane & 15, lk = lane >> 4;

    f32x4 acc[4][4];
    #pragma unroll
    for (int mi = 0; mi < 4; ++mi)
        #pragma unroll
        for (int ni = 0; ni < 4; ++ni) acc[mi][ni] = (f32x4){0.f, 0.f, 0.f, 0.f};

    #pragma unroll
    for (int kk = 0; kk < 4; ++kk) {
        s16x8 a[4], b[4];
        #pragma unroll
        for (int mi = 0; mi < 4; ++mi) {
            int row = wr * 64 + mi * 16 + lrow;
            int c16 = (lk + kk * 4) ^ (row & 7);
            a[mi] = *(const s16x8*)(As + row * 128 + c16 * 8);
        }
        #pragma unroll
        for (int ni = 0; ni < 4; ++ni) {
            int n = n0 + wc * 64 + ni * 16 + lrow;
            b[ni] = *(const s16x8*)(Bt + (size_t)n * 128 + kk * 32 + lk * 8);
        }
        #pragma unroll
        for (int mi = 0; mi < 4; ++mi)
            #pragma unroll
            for (int ni = 0; ni < 4; ++ni)
                acc[mi][ni] = __builtin_amdgcn_mfma_f32_16x16x32_bf16(
                    a[mi], b[ni], acc[mi][ni], 0, 0, 0);
    }

    if (OUT_BF16) {
        __syncthreads();
        ushort* Cl = As;
        #pragma unroll
        for (int mi = 0; mi < 4; ++mi)
            #pragma unroll
            for (int ni = 0; ni < 4; ++ni)
                #pragma unroll
                for (int r = 0; r < 4; ++r) {
                    int row = wr * 64 + mi * 16 + (lane >> 4) * 4 + r;
                    int col = wc * 64 + ni * 16 + (lane & 15);
                    float v = acc[mi][ni][r] + (bias ? bias[n0 + col] : 0.f);
                    Cl[row * 128 + (((col >> 3) ^ (row & 7)) << 3) + (col & 7)] = f2bf(v);
                }
        __syncthreads();
        ushort* C = (ushort*)Cv;
        #pragma unroll
        for (int p = 0; p < 8; ++p) {
            int c = p * 256 + tid;
            int row = c >> 4, c16 = c & 15;
            int gr = m0 + row;
            if (gr < M)
                *(int4*)(C + (size_t)gr * N + n0 + c16 * 8) =
                    *(const int4*)(As + row * 128 + (c16 ^ (row & 7)) * 8);
        }
    } else {
        float* C = (float*)Cv;
        #pragma unroll
        for (int mi = 0; mi < 4; ++mi)
            #pragma unroll
            for (int ni = 0; ni < 4; ++ni)
                #pragma unroll
                for (int r = 0; r < 4; ++r) {
                    int row = m0 + wr * 64 + mi * 16 + (lane >> 4) * 4 + r;
                    int col = n0 + wc * 64 + ni * 16 + (lane & 15);
                    if (row < M)
                        C[(size_t)row * N + col] =
                            acc[mi][ni][r] + (bias ? bias[col] : 0.f);
                }
    }
}

// ---------------------------------------------------------------------------
// Panel GEMM: A staged once, NPAN col-panels per block, direct bf16 epilogue.
// ---------------------------------------------------------------------------
template<int NPAN>
__global__ __launch_bounds__(256) void gemm_pan(
    const ushort* __restrict__ A, const ushort* __restrict__ Bt,
    const float* __restrict__ bias, ushort* __restrict__ C, int M, int N)
{
    __shared__ ushort As[128 * 128];
    const int tid = threadIdx.x;
    const int m0 = blockIdx.x * 128;

    #pragma unroll
    for (int p = 0; p < 8; ++p) {
        int c = p * 256 + tid;
        int row = c >> 4, c16 = c & 15;
        *(int4*)(As + row * 128 + (c16 ^ (row & 7)) * 8) =
            *(const int4*)(A + (size_t)(m0 + row) * 128 + c16 * 8);
    }
    __syncthreads();

    const int lane = tid & 63, wave = tid >> 6;
    const int wr = wave >> 1, wc = wave & 1;
    const int lrow = lane & 15, lk = lane >> 4;

    #pragma unroll 1
    for (int pan = 0; pan < NPAN; ++pan) {
        const int n0 = (blockIdx.y * NPAN + pan) * 128;

        f32x4 acc[4][4];
        #pragma unroll
        for (int mi = 0; mi < 4; ++mi)
            #pragma unroll
            for (int ni = 0; ni < 4; ++ni) acc[mi][ni] = (f32x4){0.f, 0.f, 0.f, 0.f};

        #pragma unroll
        for (int kk = 0; kk < 4; ++kk) {
            s16x8 a[4], b[4];
            #pragma unroll
            for (int mi = 0; mi < 4; ++mi) {
                int row = wr * 64 + mi * 16 + lrow;
                int c16 = (lk + kk * 4) ^ (row & 7);
                a[mi] = *(const s16x8*)(As + row * 128 + c16 * 8);
            }
            #pragma unroll
            for (int ni = 0; ni < 4; ++ni) {
                int n = n0 + wc * 64 + ni * 16 + lrow;
                b[ni] = *(const s16x8*)(Bt + (size_t)n * 128 + kk * 32 + lk * 8);
            }
            #pragma unroll
            for (int mi = 0; mi < 4; ++mi)
                #pragma unroll
                for (int ni = 0; ni < 4; ++ni)
                    acc[mi][ni] = __builtin_amdgcn_mfma_f32_16x16x32_bf16(
                        a[mi], b[ni], acc[mi][ni], 0, 0, 0);
        }

        #pragma unroll
        for (int mi = 0; mi < 4; ++mi)
            #pragma unroll
            for (int ni = 0; ni < 4; ++ni) {
                int col = n0 + wc * 64 + ni * 16 + (lane & 15);
                float bv = bias ? bias[col] : 0.f;
                int row = m0 + wr * 64 + mi * 16 + (lane >> 4) * 4;
                ushort* cp = C + (size_t)row * N + col;
                #pragma unroll
                for (int r = 0; r < 4; ++r) {
                    *cp = f2bf(acc[mi][ni][r] + bv);
                    cp += N;
                }
            }
    }
}

// ---------------------------------------------------------------------------
// Weight prep (round-13 layout)
// ---------------------------------------------------------------------------
__global__ void prep_mats(
    const float* __restrict__ Wk, const float* __restrict__ Wq,
    const float* __restrict__ Wv, const float* __restrict__ Ws,
    const float* __restrict__ Wgt, const float* __restrict__ Wq1,
    const float* __restrict__ Wk2, const float* __restrict__ Wv2,
    const float* __restrict__ Wo,
    ushort* __restrict__ panels, ushort* __restrict__ wssum,
    ushort* __restrict__ finalw)
{
    const int m = blockIdx.x >> 6;
    const int e = (blockIdx.x & 63) * 256 + threadIdx.x;
    const int nl = e >> 7, k = e & 127;
    const int dstlist[3][3] = {{0,3,6},{1,4,7},{2,5,-1}};
    const int srclist[3][3] = {{0,1,2},{3,4,5},{6,7,-1}};
    const int nkg[3] = {3,3,2};
    const int gofs[3] = {0,1280,2560};

    if (m < 52) {
        int l = m / 26, r = m % 26;
        int g, slot;
        if (r < 10)      { g = 0; slot = r; }
        else if (r < 20) { g = 1; slot = r - 10; }
        else             { g = 2; slot = r - 20; }
        int nk = nkg[g];
        float val; int col;
        if (slot < nk) {
            int t = dstlist[g][slot];
            val = Wk[(size_t)(l * 8 + t) * 16384 + k * 128 + nl];
            col = slot * 128 + nl;
        } else if (slot < 2 * nk) {
            int s = slot - nk; int t = srclist[g][s];
            val = Wq[(size_t)(l * 8 + t) * 16384 + k * 128 + nl];
            col = nk * 128 + s * 256 + ((nl >> 1) << 2) + (nl & 1);
        } else if (slot < 3 * nk) {
            int s = slot - 2 * nk; int t = srclist[g][s];
            val = Wv[(size_t)(l * 8 + t) * 16384 + k * 128 + nl];
            col = nk * 128 + s * 256 + ((nl >> 1) << 2) + 2 + (nl & 1);
        } else {
            float s = 0.f;
            #pragma unroll
            for (int i = 0; i < 3; ++i) {
                int t = dstlist[g][i];
                if (t >= 0) s += Ws[(size_t)(l * 8 + t) * 16384 + k * 128 + nl];
            }
            val = s; col = 1152 + nl;
        }
        panels[((size_t)l * 3328 + gofs[g] + col) * 128 + k] = f2bf(val);
    } else if (m < 54) {
        int l = m - 52;
        float s = Ws[(size_t)(l * 8 + 2) * 16384 + k * 128 + nl]
                + Ws[(size_t)(l * 8 + 5) * 16384 + k * 128 + nl];
        wssum[(size_t)l * 16384 + nl * 128 + k] = f2bf(s);
    } else {
        const float* fsrc[5] = {Wgt, Wq1, Wk2, Wv2, Wo};
        int idx = m - 54;
        finalw[(size_t)idx * 16384 + nl * 128 + k] = f2bf(fsrc[idx][k * 128 + nl]);
    }
}

__global__ void prep_bias(
    const float* __restrict__ bk, const float* __restrict__ bq,
    const float* __restrict__ bv, const float* __restrict__ bconv,
    float* __restrict__ bias_cat, float* __restrict__ bcsum)
{
    const int l = blockIdx.x / 3, g = blockIdx.x % 3;
    const int dstlist[3][3] = {{0,3,6},{1,4,7},{2,5,-1}};
    const int srclist[3][3] = {{0,1,2},{3,4,5},{6,7,-1}};
    const int nkg[3] = {3,3,2};
    const int gofs[3] = {0,1280,2560};
    const int nslots = (g < 2) ? 10 : 6;
    int nk = nkg[g];
    for (int idx = threadIdx.x; idx < nslots * 128; idx += 256) {
        int slot = idx >> 7, nl = idx & 127;
        float val; int col;
        if (slot < nk) {
            int t = dstlist[g][slot];
            val = bk[(l * 8 + t) * 128 + nl];
            col = slot * 128 + nl;
        } else if (slot < 2 * nk) {
            int s = slot - nk; int t = srclist[g][s];
            val = bq[(l * 8 + t) * 128 + nl];
            col = nk * 128 + s * 256 + ((nl >> 1) << 2) + (nl & 1);
        } else if (slot < 3 * nk) {
            int s = slot - 2 * nk; int t = srclist[g][s];
            val = bv[(l * 8 + t) * 128 + nl];
            col = nk * 128 + s * 256 + ((nl >> 1) << 2) + 2 + (nl & 1);
        } else {
            float s = 0.f;
            #pragma unroll
            for (int i = 0; i < 3; ++i) {
                int t = dstlist[g][i];
                if (t >= 0) s += bconv[(l * 8 + t) * 128 + nl];
            }
            val = s; col = 1152 + nl;
        }
        bias_cat[l * 3328 + gofs[g] + col] = val;
    }
    if (g == 2 && threadIdx.x < 128) {
        bcsum[l * 128 + threadIdx.x] =
            bconv[(l * 8 + 2) * 128 + threadIdx.x] + bconv[(l * 8 + 5) * 128 + threadIdx.x];
    }
}

// ---------------------------------------------------------------------------
// CSR build: histogram -> parallel scan -> scatter (+bf16 ea scatter)
// ---------------------------------------------------------------------------
struct HArgs {
    const int* ei[6];
    const float* eav[6];
    int E[6];
    int base[6];
    int cum[7];
};

__global__ void hist_kernel(HArgs A, int* __restrict__ bins)
{
    int g = blockIdx.x * 256 + threadIdx.x;
    if (g >= A.cum[6]) return;
    int t = 0;
    #pragma unroll
    for (int i = 0; i < 5; ++i) t += (g >= A.cum[i + 1]);
    int e = g - A.cum[t];
    int dst = A.ei[t][A.E[t] + e];
    atomicAdd(&bins[A.base[t] + dst], 1);
}

__global__ __launch_bounds__(256) void scan_a(
    const int* __restrict__ bins, int* __restrict__ offs, int* __restrict__ bsum)
{
    __shared__ int s[256];
    const int b = blockIdx.x, t = threadIdx.x;
    int v = bins[b * 256 + t];
    s[t] = v; __syncthreads();
    #pragma unroll
    for (int off = 1; off < 256; off <<= 1) {
        int x = (t >= off) ? s[t - off] : 0;
        __syncthreads();
        s[t] += x;
        __syncthreads();
    }
    offs[b * 256 + t] = s[t] - v;
    if (t == 255) bsum[b] = s[255];
}

__global__ __launch_bounds__(1024) void scan_b(
    const int* __restrict__ bsum, int* __restrict__ carry)
{
    __shared__ int s[1024];
    const int t = threadIdx.x;
    int v = bsum[t];
    s[t] = v; __syncthreads();
    for (int off = 1; off < 1024; off <<= 1) {
        int x = (t >= off) ? s[t - off] : 0;
        __syncthreads();
        s[t] += x;
        __syncthreads();
    }
    carry[t] = s[t] - v;
}

__global__ void scan_c(int* __restrict__ offs, const int* __restrict__ carry,
                       int* __restrict__ cursor)
{
    const int b = blockIdx.x, t = threadIdx.x;
    int v = offs[b * 256 + t] + carry[b];
    offs[b * 256 + t] = v;
    cursor[b * 256 + t] = v;
}

__global__ void scatter_kernel(HArgs A, int* __restrict__ cursor,
                               int* __restrict__ lsrc, int* __restrict__ leid,
                               ushort* __restrict__ eascat)
{
    int g = blockIdx.x * 256 + threadIdx.x;
    if (g >= A.cum[6]) return;
    int t = 0;
    #pragma unroll
    for (int i = 0; i < 5; ++i) t += (g >= A.cum[i + 1]);
    int e = g - A.cum[t];
    int src = A.ei[t][e];
    int dst = A.ei[t][A.E[t] + e];
    int pos = atomicAdd(&cursor[A.base[t] + dst], 1);
    lsrc[pos] = src;
    leid[pos] = e;
    if (eascat) {
        const float* eap = A.eav[t] + (size_t)e * 16;
        s16x8 lo, hi;
        #pragma unroll
        for (int r = 0; r < 8; ++r) {
            lo[r] = (short)f2bf(eap[r]);
            hi[r] = (short)f2bf(eap[r + 8]);
        }
        *(s16x8*)(eascat + (size_t)pos * 16) = lo;
        *(s16x8*)(eascat + (size_t)pos * 16 + 8) = hi;
    }
}

// ---------------------------------------------------------------------------
// CSR gather bodies
// ---------------------------------------------------------------------------
struct GTA {
    int base, kcol, qvcol, lds;
    const ushort* Ys;
    const float* ea;
    const float* We;
    const float* be;
};
struct GArgs {
    GTA t[3];
    const int* offs;
    const int* lsrc;
    const int* leid;
    const ushort* eascat;
    ushort* xbg;
    const ushort* Yg;
    int ldg, wscol;
};

// depth-2 pipeline over each type's CSR segment (SEQEA path) — round-15 best
__device__ __forceinline__ void gather_body_seq(const GArgs& A, int d, int lane)
{
    const int j0 = lane * 2;
    ushort2 w2 = *(const ushort2*)(A.Yg + (size_t)d * A.ldg + A.wscol + j0);
    float a0 = bf2f(w2.x), a1 = bf2f(w2.y);

    #pragma unroll
    for (int i = 0; i < 3; ++i) {
        const GTA T = A.t[i];
        int start = __builtin_amdgcn_readfirstlane(A.offs[T.base + d]);
        int end   = __builtin_amdgcn_readfirstlane(A.offs[T.base + d + 1]);
        if (start == end) continue;

        ushort2 kk = *(const ushort2*)(A.Yg + (size_t)d * A.ldg + T.kcol + j0);
        float k0 = bf2f(kk.x), k1 = bf2f(kk.y);
        float we0[16], we1[16];
        #pragma unroll
        for (int r = 0; r < 16; ++r) {
            float2 wv = *(const float2*)(T.We + r * 128 + j0);
            we0[r] = wv.x; we1[r] = wv.y;
        }
        float2 be2 = *(const float2*)(T.be + j0);

        int eB = (start + 1 < end) ? start + 1 : start;
        int siA = __builtin_amdgcn_readfirstlane(A.lsrc[start]);
        uint2 qvA = *(const uint2*)(T.Ys + (size_t)siA * T.lds + T.qvcol + lane * 4);
        s16x8 loA = *(const s16x8*)(A.eascat + (size_t)start * 16);
        s16x8 hiA = *(const s16x8*)(A.eascat + (size_t)start * 16 + 8);
        int siB = __builtin_amdgcn_readfirstlane(A.lsrc[eB]);
        uint2 qvB = *(const uint2*)(T.Ys + (size_t)siB * T.lds + T.qvcol + lane * 4);
        s16x8 loB = *(const s16x8*)(A.eascat + (size_t)eB * 16);
        s16x8 hiB = *(const s16x8*)(A.eascat + (size_t)eB * 16 + 8);

        #define COMPUTE_SEQ(QV, LO, HI) { \
            float c[16]; \
            _Pragma("unroll") \
            for (int r = 0; r < 8; ++r) { \
                c[r]     = bf2f((ushort)(LO)[r]); \
                c[r + 8] = bf2f((ushort)(HI)[r]); \
            } \
            float e0 = be2.x, e1 = be2.y; \
            _Pragma("unroll") \
            for (int r = 0; r < 16; ++r) { \
                e0 = fmaf(c[r], we0[r], e0); \
                e1 = fmaf(c[r], we1[r], e1); \
            } \
            float q0 = bf2f((ushort)((QV).x & 0xffff)), q1 = bf2f((ushort)((QV).x >> 16)); \
            float v0 = bf2f((ushort)((QV).y & 0xffff)), v1 = bf2f((ushort)((QV).y >> 16)); \
            float g0 = 1.f / (1.f + __expf(-(k0 + q0 + e0))); \
            float g1 = 1.f / (1.f + __expf(-(k1 + q1 + e1))); \
            a0 = fmaf(g0, v0, a0); \
            a1 = fmaf(g1, v1, a1); }

        for (int e = start; e < end; e += 2) {
            uint2 qc = qvA; s16x8 cl = loA, ch = hiA;
            int nxA = (e + 2 < end) ? e + 2 : e;
            siA = __builtin_amdgcn_readfirstlane(A.lsrc[nxA]);
            qvA = *(const uint2*)(T.Ys + (size_t)siA * T.lds + T.qvcol + lane * 4);
            loA = *(const s16x8*)(A.eascat + (size_t)nxA * 16);
            hiA = *(const s16x8*)(A.eascat + (size_t)nxA * 16 + 8);
            COMPUTE_SEQ(qc, cl, ch)

            if (e + 1 < end) {
                uint2 qc2 = qvB; s16x8 dl = loB, dh = hiB;
                int nxB = (e + 3 < end) ? e + 3 : e;
                siB = __builtin_amdgcn_readfirstlane(A.lsrc[nxB]);
                qvB = *(const uint2*)(T.Ys + (size_t)siB * T.lds + T.qvcol + lane * 4);
                loB = *(const s16x8*)(A.eascat + (size_t)nxB * 16);
                hiB = *(const s16x8*)(A.eascat + (size_t)nxB * 16 + 8);
                COMPUTE_SEQ(qc2, dl, dh)
            }
        }
        #undef COMPUTE_SEQ
    }
    ushort2 o; o.x = f2bf(fmaxf(a0, 0.f)); o.y = f2bf(fmaxf(a1, 0.f));
    *(ushort2*)(A.xbg + (size_t)d * 128 + j0) = o;
}

// merged two-group gather (SEQEA path)
struct G2Args {
    GArgs g0;
    GArgs g1;
    int nblk0;
};

__global__ __launch_bounds__(256) void gather2_kernel(G2Args P)
{
    const int wave = threadIdx.x >> 6, lane = threadIdx.x & 63;
    if ((int)blockIdx.x < P.nblk0) {
        gather_body_seq(P.g0, blockIdx.x * 4 + wave, lane);
    } else {
        gather_body_seq(P.g1, (blockIdx.x - P.nblk0) * 4 + wave, lane);
    }
}

// fallback: leid-based gather (only used if eascat doesn't fit in ws)
__global__ __launch_bounds__(256) void gather_kernel0(GArgs A)
{
    const int wave = threadIdx.x >> 6, lane = threadIdx.x & 63;
    const int d = blockIdx.x * 4 + wave;
    const int j0 = lane * 2;

    ushort2 w2 = *(const ushort2*)(A.Yg + (size_t)d * A.ldg + A.wscol + j0);
    float a0 = bf2f(w2.x), a1 = bf2f(w2.y);

    #pragma unroll
    for (int i = 0; i < 3; ++i) {
        const GTA T = A.t[i];
        int start = __builtin_amdgcn_readfirstlane(A.offs[T.base + d]);
        int end   = __builtin_amdgcn_readfirstlane(A.offs[T.base + d + 1]);
        if (start == end) continue;

        ushort2 kk = *(const ushort2*)(A.Yg + (size_t)d * A.ldg + T.kcol + j0);
        float k0 = bf2f(kk.x), k1 = bf2f(kk.y);
        float we0[16], we1[16];
        #pragma unroll
        for (int r = 0; r < 16; ++r) {
            float2 wv = *(const float2*)(T.We + r * 128 + j0);
            we0[r] = wv.x; we1[r] = wv.y;
        }
        float2 be2 = *(const float2*)(T.be + j0);

        for (int e = start; e < end; ++e) {
            int si  = __builtin_amdgcn_readfirstlane(A.lsrc[e]);
            int eid = __builtin_amdgcn_readfirstlane(A.leid[e]);
            uint2 qv = *(const uint2*)(T.Ys + (size_t)si * T.lds + T.qvcol + lane * 4);
            float4 c0 = *(const float4*)(T.ea + (size_t)eid * 16);
            float4 c1 = *(const float4*)(T.ea + (size_t)eid * 16 + 4);
            float4 c2 = *(const float4*)(T.ea + (size_t)eid * 16 + 8);
            float4 c3 = *(const float4*)(T.ea + (size_t)eid * 16 + 12);
            float e0 = be2.x, e1 = be2.y;
            e0 += c0.x*we0[0] + c0.y*we0[1] + c0.z*we0[2] + c0.w*we0[3]
                + c1.x*we0[4] + c1.y*we0[5] + c1.z*we0[6] + c1.w*we0[7]
                + c2.x*we0[8] + c2.y*we0[9] + c2.z*we0[10] + c2.w*we0[11]
                + c3.x*we0[12] + c3.y*we0[13] + c3.z*we0[14] + c3.w*we0[15];
            e1 += c0.x*we1[0] + c0.y*we1[1] + c0.z*we1[2] + c0.w*we1[3]
                + c1.x*we1[4] + c1.y*we1[5] + c1.z*we1[6] + c1.w*we1[7]
                + c2.x*we1[8] + c2.y*we1[9] + c2.z*we1[10] + c2.w*we1[11]
                + c3.x*we1[12] + c3.y*we1[13] + c3.z*we1[14] + c3.w*we1[15];
            float q0 = bf2f((ushort)(qv.x & 0xffff)), q1 = bf2f((ushort)(qv.x >> 16));
            float v0 = bf2f((ushort)(qv.y & 0xffff)), v1 = bf2f((ushort)(qv.y >> 16));
            float g0 = 1.f / (1.f + __expf(-(k0 + q0 + e0)));
            float g1 = 1.f / (1.f + __expf(-(k1 + q1 + e1)));
            a0 = fmaf(g0, v0, a0);
            a1 = fmaf(g1, v1, a1);
        }
    }
    ushort2 o; o.x = f2bf(fmaxf(a0, 0.f)); o.y = f2bf(fmaxf(a1, 0.f));
    *(ushort2*)(A.xbg + (size_t)d * 128 + j0) = o;
}

// ---------------------------------------------------------------------------
// Atomic edge kernel for Slack-destination types (qv quad-interleaved layout)
// ---------------------------------------------------------------------------
__global__ __launch_bounds__(256) void edge_slack(
    const int* __restrict__ ei, const float* __restrict__ ea,
    const float* __restrict__ We, const float* __restrict__ be,
    const ushort* __restrict__ Yk, int ldk,
    const ushort* __restrict__ Yqv, int ldq,
    float* __restrict__ nd, int E)
{
    const int e = blockIdx.x * 2 + (threadIdx.x >> 7);
    if (e >= E) return;
    const int j = threadIdx.x & 127;
    const int si = ei[e];
    const int di = ei[E + e];

    float ej = be[j];
    #pragma unroll
    for (int r = 0; r < 16; ++r)
        ej += ea[(size_t)e * 16 + r] * We[r * 128 + j];

    float kv = bf2f(Yk[(size_t)di * ldk + j]);
    float qv = bf2f(Yqv[(size_t)si * ldq + ((j >> 1) << 2) + (j & 1)]);
    float vv = bf2f(Yqv[(size_t)si * ldq + ((j >> 1) << 2) + 2 + (j & 1)]);
    float g  = 1.f / (1.f + __expf(-(kv + qv + ej)));
    atomicAdd(&nd[(size_t)di * 128 + j], g * vv);
}

// ---------------------------------------------------------------------------
// Elementwise helpers
// ---------------------------------------------------------------------------
__global__ void f2b_kernel(const float* __restrict__ a, ushort* __restrict__ o, int n)
{
    int i = (blockIdx.x * 256 + threadIdx.x) * 4;
    if (i < n) {
        float4 v = *(const float4*)(a + i);
        ushort4 u; u.x = f2bf(v.x); u.y = f2bf(v.y); u.z = f2bf(v.z); u.w = f2bf(v.w);
        *(ushort4*)(o + i) = u;
    }
}
__global__ void relu_b_kernel(const float* __restrict__ a, ushort* __restrict__ o, int n)
{
    int i = (blockIdx.x * 256 + threadIdx.x) * 4;
    if (i < n) {
        float4 v = *(const float4*)(a + i);
        ushort4 u;
        u.x = f2bf(fmaxf(v.x, 0.f)); u.y = f2bf(fmaxf(v.y, 0.f));
        u.z = f2bf(fmaxf(v.z, 0.f)); u.w = f2bf(fmaxf(v.w, 0.f));
        *(ushort4*)(o + i) = u;
    }
}
__global__ void b2f_kernel(const ushort* __restrict__ a, float* __restrict__ o, int n)
{
    int i = blockIdx.x * 256 + threadIdx.x;
    if (i < n) o[i] = bf2f(a[i]);
}

// ---------------------------------------------------------------------------
// Global pooling (bf16): two-stage mean+max
// ---------------------------------------------------------------------------
__global__ void pool1(const ushort* __restrict__ gf, float* __restrict__ pbuf)
{
    const int b = blockIdx.x >> 4, c = blockIdx.x & 15;
    const int j = threadIdx.x;
    float s = 0.f, m = -INFINITY;
    const ushort* pq = gf + (size_t)(b * 1024 + c * 64) * 128;
    for (int i = 0; i < 64; ++i) { float v = bf2f(pq[i * 128 + j]); s += v; m = fmaxf(m, v); }
    const ushort* pv = gf + (size_t)(N_PQ + b * 256 + c * 16) * 128;
    for (int i = 0; i < 16; ++i) { float v = bf2f(pv[i * 128 + j]); s += v; m = fmaxf(m, v); }
    if (c == 0) { float v = bf2f(gf[(size_t)(N_PQ + N_PV + b) * 128 + j]); s += v; m = fmaxf(m, v); }
    pbuf[(size_t)blockIdx.x * 256 + j] = s;
    pbuf[(size_t)blockIdx.x * 256 + 128 + j] = m;
}
__global__ void pool2(const float* __restrict__ pbuf, float* __restrict__ gnode)
{
    const int b = blockIdx.x, j = threadIdx.x;
    float s = 0.f, m = -INFINITY;
    for (int c = 0; c < 16; ++c) {
        s += pbuf[(size_t)(b * 16 + c) * 256 + j];
        m = fmaxf(m, pbuf[(size_t)(b * 16 + c) * 256 + 128 + j]);
    }
    gnode[(size_t)(b * 2) * 128 + j]     = s * (1.f / 1281.f);
    gnode[(size_t)(b * 2 + 1) * 128 + j] = m;
}

// ---------------------------------------------------------------------------
// Cross-attention (2 keys)
// ---------------------------------------------------------------------------
__global__ __launch_bounds__(256) void attn_kernel(
    const ushort* __restrict__ q, const float* __restrict__ k2,
    const float* __restrict__ v2, ushort* __restrict__ ao, int shift, int Ntot)
{
    const int n = blockIdx.x * 2 + (threadIdx.x >> 7);
    if (n >= Ntot) return;
    const int j = threadIdx.x & 127;
    const int b = n >> shift;
    const int h16 = j & ~15;

    const ushort* qn = q + (size_t)n * 128 + h16;
    const float* k0 = k2 + (size_t)(b * 2) * 128 + h16;
    const float* k1 = k2 + (size_t)(b * 2 + 1) * 128 + h16;
    float s0 = 0.f, s1 = 0.f;
    #pragma unroll
    for (int d = 0; d < 16; ++d) {
        float qq = bf2f(qn[d]); s0 += qq * k0[d]; s1 += qq * k1[d];
    }
    s0 *= 0.25f; s1 *= 0.25f;
    float m  = fmaxf(s0, s1);
    float a0 = __expf(s0 - m), a1 = __expf(s1 - m);
    float inv = 1.f / (a0 + a1);
    ao[(size_t)n * 128 + j] = f2bf(
        (a0 * v2[(size_t)(b * 2) * 128 + j] + a1 * v2[(size_t)(b * 2 + 1) * 128 + j]) * inv);
}

// ---------------------------------------------------------------------------
// LayerNorm (ca in bf16)
// ---------------------------------------------------------------------------
__global__ __launch_bounds__(256) void ln_kernel(
    const ushort* __restrict__ x, const ushort* __restrict__ ca,
    const float* __restrict__ g, const float* __restrict__ bb,
    float* __restrict__ out, int N)
{
    const int n = blockIdx.x * 4 + (threadIdx.x >> 6);
    if (n >= N) return;
    const int l = threadIdx.x & 63;
    const size_t base = (size_t)n * 128;
    float h0 = bf2f(x[base + l * 2])     + bf2f(ca[base + l * 2]);
    float h1 = bf2f(x[base + l * 2 + 1]) + bf2f(ca[base + l * 2 + 1]);
    float s  = h0 + h1;
    float ss = h0 * h0 + h1 * h1;
    #pragma unroll
    for (int o = 32; o; o >>= 1) { s += __shfl_xor(s, o); ss += __shfl_xor(ss, o); }
    float mu  = s * (1.f / 128.f);
    float var = ss * (1.f / 128.f) - mu * mu;
    float rs  = rsqrtf(var + 1e-5f);
    out[base + l * 2]     = (h0 - mu) * rs * g[l * 2]     + bb[l * 2];
    out[base + l * 2 + 1] = (h1 - mu) * rs * g[l * 2 + 1] + bb[l * 2 + 1];
}

// ---------------------------------------------------------------------------
// Host orchestration
// ---------------------------------------------------------------------------
extern "C" void kernel_launch(void* const* d_in, const int* in_sizes, int n_in,
                              void* d_out, int out_size, void* d_ws, size_t ws_size,
                              hipStream_t stream)
{
    const float* xin[3] = {(const float*)d_in[0], (const float*)d_in[1], (const float*)d_in[2]};
    const int NNs[3] = {N_PQ, N_PV, N_SL};
    const int ncol[3] = {1280, 1280, 768};
    const int gofs[3] = {0, 1280, 2560};

    const int*   ei[8];
    const float* ea[8];
    int          Ecnt[8];
    for (int t = 0; t < 8; ++t) {
        ei[t]   = (const int*)d_in[3 + 2 * t];
        ea[t]   = (const float*)d_in[4 + 2 * t];
        Ecnt[t] = in_sizes[3 + 2 * t] / 2;
    }
    const float* Wk    = (const float*)d_in[19];
    const float* bk    = (const float*)d_in[20];
    const float* Wq    = (const float*)d_in[21];
    const float* bq    = (const float*)d_in[22];
    const float* Wv    = (const float*)d_in[23];
    const float* bv    = (const float*)d_in[24];
    const float* Ws    = (const float*)d_in[25];
    const float* bconv = (const float*)d_in[26];
    const float* We    = (const float*)d_in[27];
    const float* be    = (const float*)d_in[28];
    const float* Wgt   = (const float*)d_in[29];
    const float* bgt   = (const float*)d_in[30];
    const float* Wq1   = (const float*)d_in[31];
    const float* Wk2   = (const float*)d_in[32];
    const float* Wv2   = (const float*)d_in[33];
    const float* Wo    = (const float*)d_in[34];
    const float* bo    = (const float*)d_in[35];
    const float* ln_g  = (const float*)d_in[36];
    const float* ln_b  = (const float*)d_in[37];

    // ---- workspace carve-up (round-13 layout) ----
    char* w = (char*)d_ws;
    ushort* Y[3];
    Y[0] = (ushort*)w; w += (size_t)N_PQ * 1280 * 2;
    Y[1] = (ushort*)w; w += (size_t)N_PV * 1280 * 2;
    Y[2] = (ushort*)w; w += (size_t)N_SL * 768 * 2;
    ushort* xb[3];
    xb[0] = (ushort*)w; w += (size_t)N_PQ * 128 * 2;
    xb[1] = (ushort*)w; w += (size_t)N_PV * 128 * 2;
    xb[2] = (ushort*)w; w += (size_t)N_SL * 128 * 2;
    ushort* panels = (ushort*)w; w += (size_t)2 * 3328 * 128 * 2;
    ushort* wssum  = (ushort*)w; w += (size_t)2 * 16384 * 2;
    ushort* finalw = (ushort*)w; w += (size_t)5 * 16384 * 2;
    float* bias_cat = (float*)w; w += 6656 * 4;
    float* bcsum    = (float*)w; w += 256 * 4;
    float* gnode    = (float*)w; w += 16384 * 4;
    ushort* gnodeb  = (ushort*)w; w += 16384 * 2;
    float* k2       = (float*)w; w += 16384 * 4;
    float* v2       = (float*)w; w += 16384 * 4;
    float* pbuf     = (float*)w; w += 1024 * 256 * 4;
    const int NBINS = 262144;
    int* bins   = (int*)w; w += (size_t)NBINS * 4;
    int* offs   = (int*)w; w += (size_t)NBINS * 4;
    int* cursor = (int*)w; w += (size_t)NBINS * 4;
    int* bsum   = (int*)w; w += 1024 * 4;
    int* carry  = (int*)w; w += 1024 * 4;
    int* lsrc   = (int*)w; w += (size_t)600064 * 4;
    int* leid   = (int*)w; w += (size_t)600064 * 4;
    size_t base_bytes = (size_t)(w - (char*)d_ws);
    size_t eascat_bytes = (size_t)600064 * 16 * 2;
    ushort* eascat = nullptr;
    if (base_bytes + eascat_bytes <= ws_size) {
        eascat = (ushort*)w; w += eascat_bytes;
    }
    // overlays into Y[0]:
    ushort* gf    = Y[0];
    ushort* qb    = Y[0];
    ushort* ao    = Y[0] + (size_t)81920 * 128;
    ushort* cbufb = Y[0] + (size_t)2 * 81920 * 128;
    float* outp = (float*)d_out;
    float* nw2 = outp + (size_t)(N_PQ + N_PV) * 128;

    const ushort* Wgt_t = finalw;
    const ushort* Wq1_t = finalw + 16384;
    const ushort* Wk2_t = finalw + 32768;
    const ushort* Wv2_t = finalw + 49152;
    const ushort* Wo_t  = finalw + 65536;

    auto gemm_b = [&](const ushort* A, const ushort* Bt, const float* bias,
                      ushort* C, int M, int N) {
        if (M >= 1024 && N % 256 == 0)
            gemm_pan<2><<<dim3(M / 128, N / 256), 256, 0, stream>>>(A, Bt, bias, C, M, N);
        else if (M >= 1024 && M % 128 == 0 && N % 128 == 0)
            gemm_pan<1><<<dim3(M / 128, N / 128), 256, 0, stream>>>(A, Bt, bias, C, M, N);
        else
            gemm_mfma<1><<<dim3((M + 127) / 128, N / 128), 256, 0, stream>>>(
                A, Bt, bias, C, M, N);
    };
    auto gemm_f = [&](const ushort* A, const ushort* Bt, const float* bias,
                      float* C, int M, int N) {
        gemm_mfma<0><<<dim3((M + 127) / 128, N / 128), 256, 0, stream>>>(A, Bt, bias, C, M, N);
    };

    // 1) weight prep + input converts
    prep_mats<<<59 * 64, 256, 0, stream>>>(Wk, Wq, Wv, Ws, Wgt, Wq1, Wk2, Wv2, Wo,
                                           panels, wssum, finalw);
    prep_bias<<<6, 256, 0, stream>>>(bk, bq, bv, bconv, bias_cat, bcsum);
    for (int g = 0; g < 3; ++g) {
        int n = NNs[g] * 128;
        f2b_kernel<<<dim3((n / 4 + 255) / 256), 256, 0, stream>>>(xin[g], xb[g], n);
    }

    // 2) CSR build
    const int csr_t[6]    = {0, 3, 6, 1, 4, 7};
    const int csr_base[6] = {0, 65536, 131072, 196608, 212992, 229376};
    HArgs ha;
    {
        int c = 0;
        for (int i = 0; i < 6; ++i) {
            int t = csr_t[i];
            ha.ei[i] = ei[t]; ha.eav[i] = ea[t];
            ha.E[i] = Ecnt[t]; ha.base[i] = csr_base[i];
            ha.cum[i] = c; c += Ecnt[t];
        }
        ha.cum[6] = c;
    }
    hipMemsetAsync(bins, 0, (size_t)NBINS * 4, stream);
    hist_kernel<<<dim3((ha.cum[6] + 255) / 256), 256, 0, stream>>>(ha, bins);
    scan_a<<<1024, 256, 0, stream>>>(bins, offs, bsum);
    scan_b<<<1, 1024, 0, stream>>>(bsum, carry);
    scan_c<<<1024, 256, 0, stream>>>(offs, carry, cursor);
    scatter_kernel<<<dim3((ha.cum[6] + 255) / 256), 256, 0, stream>>>(
        ha, cursor, lsrc, leid, eascat);

    // 3) global features
    gemm_b(xb[0], Wgt_t, bgt, gf, N_PQ + N_PV + N_SL, 128);
    pool1<<<1024, 128, 0, stream>>>(gf, pbuf);
    pool2<<<64, 128, 0, stream>>>(pbuf, gnode);
    f2b_kernel<<<dim3(16384 / 4 / 256), 256, 0, stream>>>(gnode, gnodeb, 16384);
    gemm_f(gnodeb, Wk2_t, nullptr, k2, 128, 128);
    gemm_f(gnodeb, Wv2_t, nullptr, v2, 128, 128);

    // 4) two HeteroConv layers
    for (int l = 0; l < 2; ++l) {
        for (int g = 0; g < 3; ++g)
            gemm_b(xb[g], panels + ((size_t)l * 3328 + gofs[g]) * 128,
                   bias_cat + l * 3328 + gofs[g], Y[g], NNs[g], ncol[g]);
        gemm_f(xb[2], wssum + (size_t)l * 16384, bcsum + l * 128, nw2, N_SL, 128);

        // CSR gathers: merged PQ+PV launch (or per-group fallback)
        GArgs ga[2];
        for (int g = 0; g < 2; ++g) {
            for (int i = 0; i < 3; ++i) {
                int t = csr_t[g * 3 + i], off = l * 8 + t;
                int sgrp = (i == 2) ? 2 : i;
                ga[g].t[i].base  = csr_base[g * 3 + i];
                ga[g].t[i].kcol  = i * 128;
                ga[g].t[i].lds   = ncol[sgrp];
                ga[g].t[i].qvcol = ((sgrp == 2) ? 256 : 384) + g * 256;
                ga[g].t[i].Ys    = Y[sgrp];
                ga[g].t[i].ea    = ea[t];
                ga[g].t[i].We    = We + (size_t)off * 2048;
                ga[g].t[i].be    = be + (size_t)off * 128;
            }
            ga[g].offs = offs; ga[g].lsrc = lsrc; ga[g].leid = leid;
            ga[g].eascat = eascat;
            ga[g].xbg = xb[g]; ga[g].Yg = Y[g]; ga[g].ldg = ncol[g];
            ga[g].wscol = 1152;
        }
        if (eascat) {
            G2Args p2; p2.g0 = ga[0]; p2.g1 = ga[1]; p2.nblk0 = N_PQ / 4;
            gather2_kernel<<<dim3((N_PQ + N_PV) / 4), 256, 0, stream>>>(p2);
        } else {
            gather_kernel0<<<dim3(N_PQ / 4), 256, 0, stream>>>(ga[0]);
            gather_kernel0<<<dim3(N_PV / 4), 256, 0, stream>>>(ga[1]);
        }

        // Slack destination: tiny atomic path (types 2 and 5) + relu
        {
            int off2 = l * 8 + 2;
            edge_slack<<<dim3((Ecnt[2] + 1) / 2), 256, 0, stream>>>(
                ei[2], ea[2], We + (size_t)off2 * 2048, be + (size_t)off2 * 128,
                Y[2] + 0, 768, Y[0] + 896, 1280, nw2, Ecnt[2]);
            int off5 = l * 8 + 5;
            edge_slack<<<dim3((Ecnt[5] + 1) / 2), 256, 0, stream>>>(
                ei[5], ea[5], We + (size_t)off5 * 2048, be + (size_t)off5 * 128,
                Y[2] + 128, 768, Y[1] + 896, 1280, nw2, Ecnt[5]);
        }
        relu_b_kernel<<<dim3(8), 256, 0, stream>>>(nw2, xb[2], N_SL * 128);
    }

    // 5) cross-attention + residual + LayerNorm (merged over PQ+PV)
    gemm_b(xb[0], Wq1_t, nullptr, qb, N_PQ + N_PV, 128);
    attn_kernel<<<dim3(N_PQ / 2), 256, 0, stream>>>(qb, k2, v2, ao, 10, N_PQ);
    attn_kernel<<<dim3(N_PV / 2), 256, 0, stream>>>(qb + (size_t)N_PQ * 128, k2, v2,
                                                    ao + (size_t)N_PQ * 128, 8, N_PV);
    gemm_b(ao, Wo_t, bo, cbufb, N_PQ + N_PV, 128);
    ln_kernel<<<dim3((N_PQ + N_PV) / 4), 256, 0, stream>>>(xb[0], cbufb, ln_g, ln_b,
                                                           outp, N_PQ + N_PV);
    b2f_kernel<<<dim3((N_SL * 128 + 255) / 256), 256, 0, stream>>>(
        xb[2], outp + (size_t)(N_PQ + N_PV) * 128, N_SL * 128);
}